// Round 4
// baseline (604.928 us; speedup 1.0000x reference)
//
#include <hip/hip_runtime.h>
#include <hip/hip_bf16.h>
#include <math.h>

#define D_MODEL 4096
#define N_HEADS 128
#define LATENT  512
#define ROPE_D  64
#define HEAD_D  32
#define BATCH   2
#define SEQ     1024
#define NTOK    (BATCH*SEQ)

typedef unsigned short u16;
typedef __attribute__((ext_vector_type(8))) short bf16x8;
typedef __attribute__((ext_vector_type(4))) float f32x4;

__device__ __forceinline__ u16 f2bf(float f) {
    union { float f; unsigned u; } v; v.f = f;
    unsigned r = (v.u + 0x7fffu + ((v.u >> 16) & 1u)) >> 16;
    return (u16)r;
}

__device__ __forceinline__ void gl_lds16(const u16* g, u16* l) {
    __builtin_amdgcn_global_load_lds(
        (const __attribute__((address_space(1))) unsigned int*)g,
        (__attribute__((address_space(3))) unsigned int*)l, 16, 0, 0);
}

// ---------------- cast x: fp32 -> bf16 -------------------------------------
__global__ __launch_bounds__(256)
void cast_x_kernel(const float* __restrict__ in, u16* __restrict__ out)
{
    size_t i = ((size_t)blockIdx.x * 256 + threadIdx.x) * 8;
    float4 a = *(const float4*)(in + i);
    float4 b = *(const float4*)(in + i + 4);
    u16 o[8] = {f2bf(a.x), f2bf(a.y), f2bf(a.z), f2bf(a.w),
                f2bf(b.x), f2bf(b.y), f2bf(b.z), f2bf(b.w)};
    *(bf16x8*)(out + i) = *(bf16x8*)o;
}

// ---------- cast+transpose weights: W[K][N] fp32 -> Wt[N][K] bf16 ----------
__global__ __launch_bounds__(256)
void castT_kernel(const float* __restrict__ W, u16* __restrict__ Wt,
                  int K, int N)
{
    __shared__ float tile[32][33];
    const int tid = threadIdx.x;
    const int j0 = blockIdx.x * 32;   // N dim
    const int i0 = blockIdx.y * 32;   // K dim
    #pragma unroll
    for (int it = 0; it < 4; ++it) {
        int e = tid + it * 256;
        int r = e >> 5, c = e & 31;
        tile[r][c] = (j0 + c < N) ? W[(size_t)(i0 + r) * N + j0 + c] : 0.f;
    }
    __syncthreads();
    #pragma unroll
    for (int it = 0; it < 4; ++it) {
        int e = tid + it * 256;
        int n = e >> 5, k = e & 31;
        Wt[(size_t)(j0 + n) * K + i0 + k] = f2bf(tile[k][n]);
    }
}

// ======= 256x{256,128} bf16 GEMM, 4-deep ring + counted vmcnt ==============
// C[M,N] = A[M,K] @ Bt[N,K]^T. 512 threads = 8 waves (2M x 4N).
// BK=32. LDS ring of 4 K-tiles; stage(t+3) issued after tile-t barrier;
// s_waitcnt vmcnt(2L) (never 0 mid-loop) guarantees tile t landed.
template<int BN_, int OUTF32>
__global__ __launch_bounds__(512)
void gemm256(const u16* __restrict__ A, const u16* __restrict__ Bt,
             void* __restrict__ Cout, int M, int N, int K,
             int lda, int ldb, int ldc)
{
    constexpr int WN   = BN_ / 4;        // wave cols
    constexpr int NFR  = WN / 16;        // B frags per wave (4 or 2)
    constexpr int BUFE = 8192 + BN_ * 32;

    extern __shared__ __align__(16) u16 lds[];

    const int tid  = threadIdx.x;
    const int lane = tid & 63;
    const int wave = tid >> 6;
    const int wr = wave >> 2, wc = wave & 3;
    const int l15 = lane & 15, lg = lane >> 4;

    // XCD-aware bijective swizzle (nwg % 8 == 0 for all our grids)
    const int nwg  = gridDim.x * gridDim.y;
    const int orig = blockIdx.y * gridDim.x + blockIdx.x;
    const int swz  = (orig & 7) * (nwg >> 3) + (orig >> 3);
    const int bm = (swz / gridDim.x) * 256, bn = (swz % gridDim.x) * BN_;

    const int NT = K >> 5;               // K-tiles of 32

    auto stage = [&](int t) {
        const int buf = t & 3;
        u16* bA = lds + buf * BUFE;
        u16* bB = bA + 8192;
        const int kt = t * 32;
        #pragma unroll
        for (int it = 0; it < 2; ++it) {              // A: 1024 chunks
            int f = it * 512 + tid;
            int row = f >> 2, c = f & 3;
            int sc = (c ^ (row >> 1)) & 3;
            gl_lds16(A + (size_t)(bm + row) * lda + kt + sc * 8, bA + f * 8);
        }
        #pragma unroll
        for (int it = 0; it < BN_ / 128; ++it) {      // B: BN_*4 chunks
            int f = it * 512 + tid;
            int row = f >> 2, c = f & 3;
            int sc = (c ^ (row >> 1)) & 3;
            gl_lds16(Bt + (size_t)(bn + row) * ldb + kt + sc * 8, bB + f * 8);
        }
    };

    f32x4 acc[8][NFR];
    #pragma unroll
    for (int m = 0; m < 8; ++m)
        #pragma unroll
        for (int n = 0; n < NFR; ++n) acc[m][n] = (f32x4){0.f, 0.f, 0.f, 0.f};

    stage(0); stage(1); stage(2);        // 3L loads in flight

    for (int t = 0; t < NT; ++t) {
        const int rem = NT - 1 - t;      // tiles staged beyond t still outstanding
        if constexpr (BN_ == 256) {      // L = 4 loads/thread/tile
            if (rem >= 2)      asm volatile("s_waitcnt vmcnt(8)" ::: "memory");
            else if (rem == 1) asm volatile("s_waitcnt vmcnt(4)" ::: "memory");
            else               asm volatile("s_waitcnt vmcnt(0)" ::: "memory");
        } else {                         // L = 3
            if (rem >= 2)      asm volatile("s_waitcnt vmcnt(6)" ::: "memory");
            else if (rem == 1) asm volatile("s_waitcnt vmcnt(3)" ::: "memory");
            else               asm volatile("s_waitcnt vmcnt(0)" ::: "memory");
        }
        __builtin_amdgcn_s_barrier();
        asm volatile("" ::: "memory");   // no LDS op crosses the barrier

        if (t + 3 < NT) stage(t + 3);    // in flight across the next 3 barriers

        const u16* bA = lds + (t & 3) * BUFE;
        const u16* bB = bA + 8192;

        bf16x8 af[8], bfr[NFR];
        #pragma unroll
        for (int m = 0; m < 8; ++m) {
            int row = wr * 128 + m * 16 + l15;
            af[m] = *(const bf16x8*)(bA + row * 32 + (((lg ^ (row >> 1)) & 3) << 3));
        }
        #pragma unroll
        for (int n = 0; n < NFR; ++n) {
            int row = wc * WN + n * 16 + l15;
            bfr[n] = *(const bf16x8*)(bB + row * 32 + (((lg ^ (row >> 1)) & 3) << 3));
        }
        __builtin_amdgcn_s_setprio(1);
        #pragma unroll
        for (int m = 0; m < 8; ++m)
            #pragma unroll
            for (int n = 0; n < NFR; ++n)
                acc[m][n] = __builtin_amdgcn_mfma_f32_16x16x32_bf16(
                    af[m], bfr[n], acc[m][n], 0, 0, 0);
        __builtin_amdgcn_s_setprio(0);
    }

    #pragma unroll
    for (int m = 0; m < 8; ++m)
        #pragma unroll
        for (int n = 0; n < NFR; ++n)
            #pragma unroll
            for (int ri = 0; ri < 4; ++ri) {
                int row = bm + wr * 128 + m * 16 + 4 * lg + ri;
                int col = bn + wc * WN + n * 16 + l15;
                if (col < N) {
                    float v = acc[m][n][ri];
                    if (OUTF32) ((float*)Cout)[(size_t)row * ldc + col] = v;
                    else        ((u16*)Cout)[(size_t)row * ldc + col] = f2bf(v);
                }
            }
}

// ---------- transpose v_c (in C2, stride 8192, col base 4096) -> vt --------
__global__ __launch_bounds__(256)
void vtrans_kernel(const u16* __restrict__ vc, u16* __restrict__ vt)
{
    __shared__ __align__(16) u16 tile[64][72];
    const int tid = threadIdx.x;
    const int c0 = blockIdx.x * 64;     // dim tile (0..4095)
    const int s0 = blockIdx.y * 64;     // seq tile
    const int b  = blockIdx.z;
    #pragma unroll
    for (int it = 0; it < 2; ++it) {
        int e = it * 256 + tid;
        int r = e >> 3, c8 = e & 7;
        *(bf16x8*)&tile[r][c8 * 8] =
            *(const bf16x8*)(vc + (size_t)(b * SEQ + s0 + r) * 8192 + c0 + c8 * 8);
    }
    __syncthreads();
    #pragma unroll
    for (int it = 0; it < 2; ++it) {
        int e = it * 256 + tid;
        int d = e >> 3, c8 = e & 7;
        u16 o[8];
        #pragma unroll
        for (int j = 0; j < 8; ++j) o[j] = tile[c8 * 8 + j][d];
        *(bf16x8*)(vt + (size_t)(b * D_MODEL + c0 + d) * SEQ + s0 + c8 * 8) = *(bf16x8*)o;
    }
}

// ---------------- MFMA flash attention (swapped QK, swizzled LDS) ----------
__global__ __launch_bounds__(256)
void attn_kernel(const u16* __restrict__ q_c, const u16* __restrict__ q_r,
                 const u16* __restrict__ k_c, const u16* __restrict__ k_r,
                 const u16* __restrict__ vt,  u16* __restrict__ attn_out)
{
    __shared__ __align__(16) u16 s_kc[2][64 * 32];
    __shared__ __align__(16) u16 s_kr[2][64 * 64];
    __shared__ __align__(16) u16 s_vt[2][32 * 64];
    __shared__ __align__(16) u16 s_p[4][16 * 64];

    const int tid  = threadIdx.x;
    const int lane = tid & 63;
    const int w    = tid >> 6;
    const int l15  = lane & 15, lg = lane >> 4;
    const int q0 = blockIdx.x * 64;
    const int h  = blockIdx.y;
    const int b  = blockIdx.z;
    const size_t bS = (size_t)b * SEQ;
    const int hc = h * HEAD_D;
    const float c2 = 0.1020620726159658f * 1.44269504088896f; // log2e/sqrt(96)

    const int qrow = q0 + w * 16 + l15;
    const bf16x8 qf0 = *(const bf16x8*)(q_c + (bS + qrow) * 4096 + hc + lg * 8);
    const bf16x8 qf1 = *(const bf16x8*)(q_r + (bS + qrow) * 9344 + h * ROPE_D + lg * 8);
    const bf16x8 qf2 = *(const bf16x8*)(q_r + (bS + qrow) * 9344 + h * ROPE_D + 32 + lg * 8);

    float m2 = -1e30f, lsum = 0.f;
    f32x4 oacc[2];
    oacc[0] = (f32x4){0.f, 0.f, 0.f, 0.f};
    oacc[1] = (f32x4){0.f, 0.f, 0.f, 0.f};

    auto stage = [&](int buf, int k0) {
        { int f = tid, r = f >> 2, c = f & 3;
          gl_lds16(k_c + (bS + k0 + r) * 8192 + hc + ((c ^ (r & 3)) << 3),
                   &s_kc[buf][f * 8]); }
        #pragma unroll
        for (int it = 0; it < 2; ++it) {
          int f = it * 256 + tid, r = f >> 3, c = f & 7;
          gl_lds16(k_r + (bS + k0 + r) * 9344 + ((c ^ (r & 7)) << 3),
                   &s_kr[buf][f * 8]); }
        { int f = tid, d = f >> 3, c = f & 7;
          gl_lds16(vt + ((size_t)b * D_MODEL + hc + d) * SEQ + k0 + ((c ^ (d & 7)) << 3),
                   &s_vt[buf][f * 8]); }
    };

    stage(0, 0);
    __syncthreads();

    int cur = 0;
    for (int t = 0; t < SEQ / 64; ++t) {
        if (t + 1 < SEQ / 64) stage(cur ^ 1, (t + 1) * 64);

        f32x4 sc[4];
        #pragma unroll
        for (int fc = 0; fc < 4; ++fc) sc[fc] = (f32x4){0.f, 0.f, 0.f, 0.f};
        __builtin_amdgcn_s_setprio(1);
        #pragma unroll
        for (int fc = 0; fc < 4; ++fc) {
            int row = fc * 16 + l15;
            bf16x8 kb = *(const bf16x8*)&s_kc[cur][row * 32 + ((lg ^ (row & 3)) << 3)];
            sc[fc] = __builtin_amdgcn_mfma_f32_16x16x32_bf16(kb, qf0, sc[fc], 0, 0, 0);
        }
        #pragma unroll
        for (int tt = 0; tt < 2; ++tt) {
            bf16x8 qf = tt ? qf2 : qf1;
            #pragma unroll
            for (int fc = 0; fc < 4; ++fc) {
                int row = fc * 16 + l15;
                bf16x8 kb = *(const bf16x8*)&s_kr[cur][row * 64 + (((tt * 4 + lg) ^ (row & 7)) << 3)];
                sc[fc] = __builtin_amdgcn_mfma_f32_16x16x32_bf16(kb, qf, sc[fc], 0, 0, 0);
            }
        }
        __builtin_amdgcn_s_setprio(0);

        float tmx = sc[0][0];
        #pragma unroll
        for (int fc = 0; fc < 4; ++fc)
            #pragma unroll
            for (int ri = 0; ri < 4; ++ri)
                tmx = fmaxf(tmx, sc[fc][ri]);
        tmx = fmaxf(tmx, __shfl_xor(tmx, 16));
        tmx = fmaxf(tmx, __shfl_xor(tmx, 32));
        float tl2 = tmx * c2;
        if (!__all(tl2 <= m2 + 8.f)) {
            float mn = fmaxf(m2, tl2);
            float corr = exp2f(m2 - mn);
            m2 = mn;
            lsum *= corr;
            #pragma unroll
            for (int ri = 0; ri < 4; ++ri) {
                float cr = __shfl(corr, 4 * lg + ri);
                oacc[0][ri] *= cr; oacc[1][ri] *= cr;
            }
        }
        float rs = 0.f;
        unsigned pk0[4], pk1[4];
        #pragma unroll
        for (int fc = 0; fc < 4; ++fc) {
            float p0 = exp2f(fmaf(sc[fc][0], c2, -m2));
            float p1 = exp2f(fmaf(sc[fc][1], c2, -m2));
            float p2 = exp2f(fmaf(sc[fc][2], c2, -m2));
            float p3 = exp2f(fmaf(sc[fc][3], c2, -m2));
            rs += (p0 + p1) + (p2 + p3);
            asm("v_cvt_pk_bf16_f32 %0, %1, %2" : "=v"(pk0[fc]) : "v"(p0), "v"(p1));
            asm("v_cvt_pk_bf16_f32 %0, %1, %2" : "=v"(pk1[fc]) : "v"(p2), "v"(p3));
        }
        rs += __shfl_xor(rs, 16);
        rs += __shfl_xor(rs, 32);
        lsum += rs;
        #pragma unroll
        for (int fc = 0; fc < 4; ++fc) {
            int ch = (2 * fc + (lg >> 1)) ^ (l15 & 7);
            *(uint2*)&s_p[w][l15 * 64 + ch * 8 + 4 * (lg & 1)] =
                make_uint2(pk0[fc], pk1[fc]);
        }

        __builtin_amdgcn_s_setprio(1);
        #pragma unroll
        for (int t2 = 0; t2 < 2; ++t2) {
            bf16x8 pa = *(const bf16x8*)&s_p[w][l15 * 64 + (((t2 * 4 + lg) ^ (l15 & 7)) << 3)];
            #pragma unroll
            for (int fd = 0; fd < 2; ++fd) {
                int row = fd * 16 + l15;
                bf16x8 vb = *(const bf16x8*)&s_vt[cur][row * 64 + (((t2 * 4 + lg) ^ (row & 7)) << 3)];
                oacc[fd] = __builtin_amdgcn_mfma_f32_16x16x32_bf16(pa, vb, oacc[fd], 0, 0, 0);
            }
        }
        __builtin_amdgcn_s_setprio(0);

        __syncthreads();
        cur ^= 1;
    }

    #pragma unroll
    for (int ri = 0; ri < 4; ++ri) {
        float ls = __shfl(lsum, 4 * lg + ri);
        float inv = 1.f / ls;
        int row = q0 + w * 16 + 4 * lg + ri;
        attn_out[(bS + row) * 4096 + hc + l15]      = f2bf(oacc[0][ri] * inv);
        attn_out[(bS + row) * 4096 + hc + 16 + l15] = f2bf(oacc[1][ri] * inv);
    }
}

// ---------------------------------------------------------------------------
extern "C" void kernel_launch(void* const* d_in, const int* in_sizes, int n_in,
                              void* d_out, int out_size, void* d_ws, size_t ws_size,
                              hipStream_t stream)
{
    (void)in_sizes; (void)n_in; (void)out_size; (void)ws_size;

    const float* x        = (const float*)d_in[0];
    const float* Wq_down  = (const float*)d_in[1];
    const float* Wq_up    = (const float*)d_in[2];
    const float* Wq_rope  = (const float*)d_in[3];
    const float* Wkv_down = (const float*)d_in[4];
    const float* Wk_up    = (const float*)d_in[5];
    const float* Wv_up    = (const float*)d_in[6];
    const float* Wk_rope  = (const float*)d_in[7];
    const float* Wo       = (const float*)d_in[8];

    // workspace (u16 units), ~180 MB total
    u16* ws   = (u16*)d_ws;
    u16* xb   = ws;                                  //  8,388,608 (x bf16; later attn_out)
    u16* BigT = xb + (size_t)8388608;                // 38,797,312 (9472 x 4096, rows 9344+ pad)
    u16* UpT  = BigT + (size_t)38797312;             //  4,194,304 (8192 x 512)
    u16* WuqT = UpT + (size_t)4194304;               //  2,097,152 (4096 x 512)
    u16* C_big= WuqT + (size_t)2097152;              // 19,136,512 (2048 x 9344)
    u16* C2   = C_big + (size_t)19136512;            // 16,777,216 (2048 x 8192: k_c|v_c)
    u16* WoT  = BigT;                                // after GEMM1
    u16* vt   = BigT + (size_t)16777216;
    u16* q_c  = BigT + (size_t)25165824;
    u16* attn_out = xb;

    dim3 blk(256);

    (void)hipFuncSetAttribute((const void*)&gemm256<256,0>,
                              hipFuncAttributeMaxDynamicSharedMemorySize, 131072);
    (void)hipFuncSetAttribute((const void*)&gemm256<128,0>,
                              hipFuncAttributeMaxDynamicSharedMemorySize, 98304);
    (void)hipFuncSetAttribute((const void*)&gemm256<128,1>,
                              hipFuncAttributeMaxDynamicSharedMemorySize, 98304);

    // zero pad rows 9280..9471 of BigT (covers Wk_rope pad + 256-tile pad)
    hipMemsetAsync(BigT + (size_t)9280 * 4096, 0, (size_t)192 * 4096 * 2, stream);
    hipLaunchKernelGGL(cast_x_kernel, dim3(4096), blk, 0, stream, x, xb);
    // BigT rows: [0,8192)=Wq_rope^T, [8192,8704)=Wq_down^T, [8704,9216)=Wkv_down^T, [9216,9280)=Wk_rope^T
    hipLaunchKernelGGL(castT_kernel, dim3(256, 128), blk, 0, stream, Wq_rope, BigT, 4096, 8192);
    hipLaunchKernelGGL(castT_kernel, dim3(16, 128), blk, 0, stream, Wq_down, BigT + (size_t)8192 * 4096, 4096, 512);
    hipLaunchKernelGGL(castT_kernel, dim3(16, 128), blk, 0, stream, Wkv_down, BigT + (size_t)8704 * 4096, 4096, 512);
    hipLaunchKernelGGL(castT_kernel, dim3(2, 128), blk, 0, stream, Wk_rope, BigT + (size_t)9216 * 4096, 4096, 64);
    hipLaunchKernelGGL(castT_kernel, dim3(128, 16), blk, 0, stream, Wk_up, UpT, 512, 4096);
    hipLaunchKernelGGL(castT_kernel, dim3(128, 16), blk, 0, stream, Wv_up, UpT + (size_t)4096 * 512, 512, 4096);
    hipLaunchKernelGGL(castT_kernel, dim3(128, 16), blk, 0, stream, Wq_up, WuqT, 512, 4096);

    // GEMM1: C_big = xb @ BigT^T   (N=9344 padded to 9472 in B)
    gemm256<256,0><<<dim3(37, 8), dim3(512), 131072, stream>>>(
        xb, BigT, C_big, NTOK, 9344, 4096, 4096, 4096, 9344);
    // Wo^T into freed BigT
    hipLaunchKernelGGL(castT_kernel, dim3(128, 128), blk, 0, stream, Wo, WoT, 4096, 4096);
    // GEMM2: k_c|v_c = c_kv @ [Wk_up|Wv_up]^T
    gemm256<256,0><<<dim3(32, 8), dim3(512), 131072, stream>>>(
        C_big + 8704, UpT, C2, NTOK, 8192, 512, 9344, 512, 8192);
    // GEMM3: q_c = c_q @ Wq_up^T
    gemm256<128,0><<<dim3(32, 8), dim3(512), 98304, stream>>>(
        C_big + 8192, WuqT, q_c, NTOK, 4096, 512, 9344, 512, 4096);
    // V transpose, attention
    hipLaunchKernelGGL(vtrans_kernel, dim3(64, 16, 2), blk, 0, stream, C2 + 4096, vt);
    hipLaunchKernelGGL(attn_kernel, dim3(16, 128, 2), blk, 0, stream,
                       q_c, C_big, C2, C_big + 9216, vt, attn_out);
    // output projection (fp32 out)
    gemm256<128,1><<<dim3(32, 8), dim3(512), 98304, stream>>>(
        attn_out, WoT, d_out, NTOK, 4096, 4096, 4096, 4096, 4096);
}

// Round 5
// 584.253 us; speedup vs baseline: 1.0354x; 1.0354x over previous
//
#include <hip/hip_runtime.h>
#include <hip/hip_bf16.h>
#include <math.h>

#define D_MODEL 4096
#define N_HEADS 128
#define LATENT  512
#define ROPE_D  64
#define HEAD_D  32
#define BATCH   2
#define SEQ     1024
#define NTOK    (BATCH*SEQ)

typedef unsigned short u16;
typedef __attribute__((ext_vector_type(8))) short bf16x8;
typedef __attribute__((ext_vector_type(4))) float f32x4;

__device__ __forceinline__ u16 f2bf(float f) {
    union { float f; unsigned u; } v; v.f = f;
    unsigned r = (v.u + 0x7fffu + ((v.u >> 16) & 1u)) >> 16;
    return (u16)r;
}

__device__ __forceinline__ void gl_lds16(const u16* g, u16* l) {
    __builtin_amdgcn_global_load_lds(
        (const __attribute__((address_space(1))) unsigned int*)g,
        (__attribute__((address_space(3))) unsigned int*)l, 16, 0, 0);
}

// ---------------- cast x: fp32 -> bf16 -------------------------------------
__global__ __launch_bounds__(256)
void cast_x_kernel(const float* __restrict__ in, u16* __restrict__ out)
{
    size_t i = ((size_t)blockIdx.x * 256 + threadIdx.x) * 8;
    float4 a = *(const float4*)(in + i);
    float4 b = *(const float4*)(in + i + 4);
    u16 o[8] = {f2bf(a.x), f2bf(a.y), f2bf(a.z), f2bf(a.w),
                f2bf(b.x), f2bf(b.y), f2bf(b.z), f2bf(b.w)};
    *(bf16x8*)(out + i) = *(bf16x8*)o;
}

// ---------- cast+transpose weights: W[K][N] fp32 -> Wt[N][K] bf16 ----------
__global__ __launch_bounds__(256)
void castT_kernel(const float* __restrict__ W, u16* __restrict__ Wt,
                  int K, int N)
{
    __shared__ float tile[32][33];
    const int tid = threadIdx.x;
    const int j0 = blockIdx.x * 32;   // N dim
    const int i0 = blockIdx.y * 32;   // K dim
    #pragma unroll
    for (int it = 0; it < 4; ++it) {
        int e = tid + it * 256;
        int r = e >> 5, c = e & 31;
        tile[r][c] = (j0 + c < N) ? W[(size_t)(i0 + r) * N + j0 + c] : 0.f;
    }
    __syncthreads();
    #pragma unroll
    for (int it = 0; it < 4; ++it) {
        int e = tid + it * 256;
        int n = e >> 5, k = e & 31;
        Wt[(size_t)(j0 + n) * K + i0 + k] = f2bf(tile[k][n]);
    }
}

// ======= 256x128 bf16 GEMM — fine-phase pipeline, ring-3, counted vmcnt ====
// C[M,N] = A[M,K] @ Bt[N,K]^T. 512 thr = 8 waves (2M x 4N), wave tile 128x32.
// BK=64; K-tile t lives in slot t%3. Phase (t,s): ds_read slice s of tile t,
// stage half of tile t+2, barrier, 16 MFMA, barrier. vmcnt(6) once per tile.
template<int OUTF32>
__global__ __launch_bounds__(512)
void gemm8p(const u16* __restrict__ A, const u16* __restrict__ Bt,
            void* __restrict__ Cout, int M, int N, int K,
            int lda, int ldb, int ldc)
{
    constexpr int TILE_A = 256 * 64;          // elems
    constexpr int TILE_B = 128 * 64;
    constexpr int SLOT   = TILE_A + TILE_B;   // 24576 elems = 48 KiB

    extern __shared__ __align__(16) u16 lds[];   // 3 slots = 144 KiB

    const int tid  = threadIdx.x;
    const int lane = tid & 63;
    const int wave = tid >> 6;
    const int wr = wave >> 2, wc = wave & 3;
    const int l15 = lane & 15, lg = lane >> 4;

    const int nwg  = gridDim.x * gridDim.y;
    const int orig = blockIdx.y * gridDim.x + blockIdx.x;
    const int swz  = (orig & 7) * (nwg >> 3) + (orig >> 3);
    const int bm = (swz / gridDim.x) * 256, bn = (swz % gridDim.x) * 128;

    const int NT = K >> 6;

    auto stageA = [&](int t) {
        u16* base = lds + (t % 3) * SLOT;
        const int kt = t << 6;
        #pragma unroll
        for (int it = 0; it < 4; ++it) {
            int f = it * 512 + tid;           // 0..2047
            int row = f >> 3, c = f & 7;
            int sc = c ^ (row & 7);
            gl_lds16(A + (size_t)(bm + row) * lda + kt + sc * 8, base + f * 8);
        }
    };
    auto stageB = [&](int t) {
        u16* base = lds + (t % 3) * SLOT + TILE_A;
        const int kt = t << 6;
        #pragma unroll
        for (int it = 0; it < 2; ++it) {
            int f = it * 512 + tid;           // 0..1023
            int row = f >> 3, c = f & 7;
            int sc = c ^ (row & 7);
            gl_lds16(Bt + (size_t)(bn + row) * ldb + kt + sc * 8, base + f * 8);
        }
    };

    f32x4 acc[8][2];
    #pragma unroll
    for (int m = 0; m < 8; ++m) {
        acc[m][0] = (f32x4){0.f, 0.f, 0.f, 0.f};
        acc[m][1] = (f32x4){0.f, 0.f, 0.f, 0.f};
    }

    // prologue: tiles 0,1 staged (12 loads/thread); confirm tile 0
    stageA(0); stageB(0); stageA(1); stageB(1);
    asm volatile("s_waitcnt vmcnt(6)" ::: "memory");
    __builtin_amdgcn_sched_barrier(0);
    __builtin_amdgcn_s_barrier();
    __builtin_amdgcn_sched_barrier(0);

    for (int t = 0; t < NT; ++t) {
        const u16* bA = lds + (t % 3) * SLOT;
        const u16* bB = bA + TILE_A;
        #pragma unroll
        for (int s = 0; s < 2; ++s) {
            // ---- ds_read register subtile (data confirmed last phase) ----
            bf16x8 af[8], bfr[2];
            #pragma unroll
            for (int m = 0; m < 8; ++m) {
                int row = wr * 128 + m * 16 + l15;
                int ch = (s * 4 + lg) ^ (row & 7);
                af[m] = *(const bf16x8*)(bA + row * 64 + ch * 8);
            }
            #pragma unroll
            for (int n = 0; n < 2; ++n) {
                int row = wc * 32 + n * 16 + l15;
                int ch = (s * 4 + lg) ^ (row & 7);
                bfr[n] = *(const bf16x8*)(bB + row * 64 + ch * 8);
            }
            // ---- stage half of tile t+2; vmcnt once per tile (odd phase) --
            if (s == 0) {
                if (t + 2 < NT) stageA(t + 2);
            } else {
                if (t + 2 < NT) stageB(t + 2);
                if (t + 1 < NT) {
                    if (t + 2 < NT) asm volatile("s_waitcnt vmcnt(6)" ::: "memory");
                    else            asm volatile("s_waitcnt vmcnt(0)" ::: "memory");
                }
            }
            // ---- barrier 1 ----
            asm volatile("" ::: "memory");
            __builtin_amdgcn_sched_barrier(0);
            __builtin_amdgcn_s_barrier();
            __builtin_amdgcn_sched_barrier(0);
            // ---- MFMA cluster (compiler inserts lgkm waits here) ----
            __builtin_amdgcn_s_setprio(1);
            #pragma unroll
            for (int m = 0; m < 8; ++m) {
                acc[m][0] = __builtin_amdgcn_mfma_f32_16x16x32_bf16(af[m], bfr[0], acc[m][0], 0, 0, 0);
                acc[m][1] = __builtin_amdgcn_mfma_f32_16x16x32_bf16(af[m], bfr[1], acc[m][1], 0, 0, 0);
            }
            __builtin_amdgcn_s_setprio(0);
            // ---- barrier 2 (reads complete before anyone restages) ----
            __builtin_amdgcn_sched_barrier(0);
            __builtin_amdgcn_s_barrier();
            __builtin_amdgcn_sched_barrier(0);
            asm volatile("" ::: "memory");
        }
    }

    #pragma unroll
    for (int m = 0; m < 8; ++m)
        #pragma unroll
        for (int n = 0; n < 2; ++n)
            #pragma unroll
            for (int ri = 0; ri < 4; ++ri) {
                int row = bm + wr * 128 + m * 16 + 4 * lg + ri;
                int col = bn + wc * 32 + n * 16 + l15;
                float v = acc[m][n][ri];
                if (OUTF32) ((float*)Cout)[(size_t)row * ldc + col] = v;
                else        ((u16*)Cout)[(size_t)row * ldc + col] = f2bf(v);
            }
}

// ---------- transpose v_c (in C2, stride 8192, col base 4096) -> vt --------
__global__ __launch_bounds__(256)
void vtrans_kernel(const u16* __restrict__ vc, u16* __restrict__ vt)
{
    __shared__ __align__(16) u16 tile[64][72];
    const int tid = threadIdx.x;
    const int c0 = blockIdx.x * 64;
    const int s0 = blockIdx.y * 64;
    const int b  = blockIdx.z;
    #pragma unroll
    for (int it = 0; it < 2; ++it) {
        int e = it * 256 + tid;
        int r = e >> 3, c8 = e & 7;
        *(bf16x8*)&tile[r][c8 * 8] =
            *(const bf16x8*)(vc + (size_t)(b * SEQ + s0 + r) * 8192 + c0 + c8 * 8);
    }
    __syncthreads();
    #pragma unroll
    for (int it = 0; it < 2; ++it) {
        int e = it * 256 + tid;
        int d = e >> 3, c8 = e & 7;
        u16 o[8];
        #pragma unroll
        for (int j = 0; j < 8; ++j) o[j] = tile[c8 * 8 + j][d];
        *(bf16x8*)(vt + (size_t)(b * D_MODEL + c0 + d) * SEQ + s0 + c8 * 8) = *(bf16x8*)o;
    }
}

// ---------------- MFMA flash attention (swapped QK, swizzled LDS) ----------
__global__ __launch_bounds__(256)
void attn_kernel(const u16* __restrict__ q_c, const u16* __restrict__ q_r,
                 const u16* __restrict__ k_c, const u16* __restrict__ k_r,
                 const u16* __restrict__ vt,  u16* __restrict__ attn_out)
{
    __shared__ __align__(16) u16 s_kc[2][64 * 32];
    __shared__ __align__(16) u16 s_kr[2][64 * 64];
    __shared__ __align__(16) u16 s_vt[2][32 * 64];
    __shared__ __align__(16) u16 s_p[4][16 * 64];

    const int tid  = threadIdx.x;
    const int lane = tid & 63;
    const int w    = tid >> 6;
    const int l15  = lane & 15, lg = lane >> 4;
    const int q0 = blockIdx.x * 64;
    const int h  = blockIdx.y;
    const int b  = blockIdx.z;
    const size_t bS = (size_t)b * SEQ;
    const int hc = h * HEAD_D;
    const float c2 = 0.1020620726159658f * 1.44269504088896f; // log2e/sqrt(96)

    const int qrow = q0 + w * 16 + l15;
    const bf16x8 qf0 = *(const bf16x8*)(q_c + (bS + qrow) * 4096 + hc + lg * 8);
    const bf16x8 qf1 = *(const bf16x8*)(q_r + (bS + qrow) * 9344 + h * ROPE_D + lg * 8);
    const bf16x8 qf2 = *(const bf16x8*)(q_r + (bS + qrow) * 9344 + h * ROPE_D + 32 + lg * 8);

    float m2 = -1e30f, lsum = 0.f;
    f32x4 oacc[2];
    oacc[0] = (f32x4){0.f, 0.f, 0.f, 0.f};
    oacc[1] = (f32x4){0.f, 0.f, 0.f, 0.f};

    auto stage = [&](int buf, int k0) {
        { int f = tid, r = f >> 2, c = f & 3;
          gl_lds16(k_c + (bS + k0 + r) * 8192 + hc + ((c ^ (r & 3)) << 3),
                   &s_kc[buf][f * 8]); }
        #pragma unroll
        for (int it = 0; it < 2; ++it) {
          int f = it * 256 + tid, r = f >> 3, c = f & 7;
          gl_lds16(k_r + (bS + k0 + r) * 9344 + ((c ^ (r & 7)) << 3),
                   &s_kr[buf][f * 8]); }
        { int f = tid, d = f >> 3, c = f & 7;
          gl_lds16(vt + ((size_t)b * D_MODEL + hc + d) * SEQ + k0 + ((c ^ (d & 7)) << 3),
                   &s_vt[buf][f * 8]); }
    };

    stage(0, 0);
    __syncthreads();

    int cur = 0;
    for (int t = 0; t < SEQ / 64; ++t) {
        if (t + 1 < SEQ / 64) stage(cur ^ 1, (t + 1) * 64);

        f32x4 sc[4];
        #pragma unroll
        for (int fc = 0; fc < 4; ++fc) sc[fc] = (f32x4){0.f, 0.f, 0.f, 0.f};
        __builtin_amdgcn_s_setprio(1);
        #pragma unroll
        for (int fc = 0; fc < 4; ++fc) {
            int row = fc * 16 + l15;
            bf16x8 kb = *(const bf16x8*)&s_kc[cur][row * 32 + ((lg ^ (row & 3)) << 3)];
            sc[fc] = __builtin_amdgcn_mfma_f32_16x16x32_bf16(kb, qf0, sc[fc], 0, 0, 0);
        }
        #pragma unroll
        for (int tt = 0; tt < 2; ++tt) {
            bf16x8 qf = tt ? qf2 : qf1;
            #pragma unroll
            for (int fc = 0; fc < 4; ++fc) {
                int row = fc * 16 + l15;
                bf16x8 kb = *(const bf16x8*)&s_kr[cur][row * 64 + (((tt * 4 + lg) ^ (row & 7)) << 3)];
                sc[fc] = __builtin_amdgcn_mfma_f32_16x16x32_bf16(kb, qf, sc[fc], 0, 0, 0);
            }
        }
        __builtin_amdgcn_s_setprio(0);

        float tmx = sc[0][0];
        #pragma unroll
        for (int fc = 0; fc < 4; ++fc)
            #pragma unroll
            for (int ri = 0; ri < 4; ++ri)
                tmx = fmaxf(tmx, sc[fc][ri]);
        tmx = fmaxf(tmx, __shfl_xor(tmx, 16));
        tmx = fmaxf(tmx, __shfl_xor(tmx, 32));
        float tl2 = tmx * c2;
        if (!__all(tl2 <= m2 + 8.f)) {
            float mn = fmaxf(m2, tl2);
            float corr = exp2f(m2 - mn);
            m2 = mn;
            lsum *= corr;
            #pragma unroll
            for (int ri = 0; ri < 4; ++ri) {
                float cr = __shfl(corr, 4 * lg + ri);
                oacc[0][ri] *= cr; oacc[1][ri] *= cr;
            }
        }
        float rs = 0.f;
        unsigned pk0[4], pk1[4];
        #pragma unroll
        for (int fc = 0; fc < 4; ++fc) {
            float p0 = exp2f(fmaf(sc[fc][0], c2, -m2));
            float p1 = exp2f(fmaf(sc[fc][1], c2, -m2));
            float p2 = exp2f(fmaf(sc[fc][2], c2, -m2));
            float p3 = exp2f(fmaf(sc[fc][3], c2, -m2));
            rs += (p0 + p1) + (p2 + p3);
            asm("v_cvt_pk_bf16_f32 %0, %1, %2" : "=v"(pk0[fc]) : "v"(p0), "v"(p1));
            asm("v_cvt_pk_bf16_f32 %0, %1, %2" : "=v"(pk1[fc]) : "v"(p2), "v"(p3));
        }
        rs += __shfl_xor(rs, 16);
        rs += __shfl_xor(rs, 32);
        lsum += rs;
        #pragma unroll
        for (int fc = 0; fc < 4; ++fc) {
            int ch = (2 * fc + (lg >> 1)) ^ (l15 & 7);
            *(uint2*)&s_p[w][l15 * 64 + ch * 8 + 4 * (lg & 1)] =
                make_uint2(pk0[fc], pk1[fc]);
        }

        __builtin_amdgcn_s_setprio(1);
        #pragma unroll
        for (int t2 = 0; t2 < 2; ++t2) {
            bf16x8 pa = *(const bf16x8*)&s_p[w][l15 * 64 + (((t2 * 4 + lg) ^ (l15 & 7)) << 3)];
            #pragma unroll
            for (int fd = 0; fd < 2; ++fd) {
                int row = fd * 16 + l15;
                bf16x8 vb = *(const bf16x8*)&s_vt[cur][row * 64 + (((t2 * 4 + lg) ^ (row & 7)) << 3)];
                oacc[fd] = __builtin_amdgcn_mfma_f32_16x16x32_bf16(pa, vb, oacc[fd], 0, 0, 0);
            }
        }
        __builtin_amdgcn_s_setprio(0);

        __syncthreads();
        cur ^= 1;
    }

    #pragma unroll
    for (int ri = 0; ri < 4; ++ri) {
        float ls = __shfl(lsum, 4 * lg + ri);
        float inv = 1.f / ls;
        int row = q0 + w * 16 + 4 * lg + ri;
        attn_out[(bS + row) * 4096 + hc + l15]      = f2bf(oacc[0][ri] * inv);
        attn_out[(bS + row) * 4096 + hc + 16 + l15] = f2bf(oacc[1][ri] * inv);
    }
}

// ---------------------------------------------------------------------------
extern "C" void kernel_launch(void* const* d_in, const int* in_sizes, int n_in,
                              void* d_out, int out_size, void* d_ws, size_t ws_size,
                              hipStream_t stream)
{
    (void)in_sizes; (void)n_in; (void)out_size; (void)ws_size;

    const float* x        = (const float*)d_in[0];
    const float* Wq_down  = (const float*)d_in[1];
    const float* Wq_up    = (const float*)d_in[2];
    const float* Wq_rope  = (const float*)d_in[3];
    const float* Wkv_down = (const float*)d_in[4];
    const float* Wk_up    = (const float*)d_in[5];
    const float* Wv_up    = (const float*)d_in[6];
    const float* Wk_rope  = (const float*)d_in[7];
    const float* Wo       = (const float*)d_in[8];

    // workspace (u16 units), ~179 MB total
    u16* ws   = (u16*)d_ws;
    u16* xb   = ws;                                  //  8,388,608 (x bf16; later attn_out)
    u16* BigT = xb + (size_t)8388608;                // 38,797,312 (9472 x 4096)
    u16* UpT  = BigT + (size_t)38797312;             //  4,194,304 (8192 x 512)
    u16* WuqT = UpT + (size_t)4194304;               //  2,097,152 (4096 x 512)
    u16* C_big= WuqT + (size_t)2097152;              // 19,136,512 (2048 x 9344)
    u16* C2   = C_big + (size_t)19136512;            // 16,777,216 (2048 x 8192: k_c|v_c)
    u16* WoT  = BigT;                                // after GEMM1
    u16* vt   = BigT + (size_t)16777216;
    u16* q_c  = BigT + (size_t)25165824;
    u16* attn_out = xb;

    dim3 blk(256);

    (void)hipFuncSetAttribute((const void*)&gemm8p<0>,
                              hipFuncAttributeMaxDynamicSharedMemorySize, 147456);
    (void)hipFuncSetAttribute((const void*)&gemm8p<1>,
                              hipFuncAttributeMaxDynamicSharedMemorySize, 147456);

    // zero pad rows 9280..9343 of BigT (Wk_rope pad inside N=9344)
    hipMemsetAsync(BigT + (size_t)9280 * 4096, 0, (size_t)64 * 4096 * 2, stream);
    hipLaunchKernelGGL(cast_x_kernel, dim3(4096), blk, 0, stream, x, xb);
    // BigT rows: [0,8192)=Wq_rope^T, [8192,8704)=Wq_down^T, [8704,9216)=Wkv_down^T, [9216,9280)=Wk_rope^T
    hipLaunchKernelGGL(castT_kernel, dim3(256, 128), blk, 0, stream, Wq_rope, BigT, 4096, 8192);
    hipLaunchKernelGGL(castT_kernel, dim3(16, 128), blk, 0, stream, Wq_down, BigT + (size_t)8192 * 4096, 4096, 512);
    hipLaunchKernelGGL(castT_kernel, dim3(16, 128), blk, 0, stream, Wkv_down, BigT + (size_t)8704 * 4096, 4096, 512);
    hipLaunchKernelGGL(castT_kernel, dim3(2, 128), blk, 0, stream, Wk_rope, BigT + (size_t)9216 * 4096, 4096, 64);
    hipLaunchKernelGGL(castT_kernel, dim3(128, 16), blk, 0, stream, Wk_up, UpT, 512, 4096);
    hipLaunchKernelGGL(castT_kernel, dim3(128, 16), blk, 0, stream, Wv_up, UpT + (size_t)4096 * 512, 512, 4096);
    hipLaunchKernelGGL(castT_kernel, dim3(128, 16), blk, 0, stream, Wq_up, WuqT, 512, 4096);

    // GEMM1: C_big = xb @ BigT^T  (M=2048, N=9344=73*128, K=4096)
    gemm8p<0><<<dim3(73, 8), dim3(512), 147456, stream>>>(
        xb, BigT, C_big, NTOK, 9344, 4096, 4096, 4096, 9344);
    // Wo^T into freed BigT
    hipLaunchKernelGGL(castT_kernel, dim3(128, 128), blk, 0, stream, Wo, WoT, 4096, 4096);
    // GEMM2: k_c|v_c = c_kv @ [Wk_up|Wv_up]^T  (N=8192, K=512)
    gemm8p<0><<<dim3(64, 8), dim3(512), 147456, stream>>>(
        C_big + 8704, UpT, C2, NTOK, 8192, 512, 9344, 512, 8192);
    // GEMM3: q_c = c_q @ Wq_up^T  (N=4096, K=512)
    gemm8p<0><<<dim3(32, 8), dim3(512), 147456, stream>>>(
        C_big + 8192, WuqT, q_c, NTOK, 4096, 512, 9344, 512, 4096);
    // V transpose, attention
    hipLaunchKernelGGL(vtrans_kernel, dim3(64, 16, 2), blk, 0, stream, C2 + 4096, vt);
    hipLaunchKernelGGL(attn_kernel, dim3(16, 128, 2), blk, 0, stream,
                       q_c, C_big, C2, C_big + 9216, vt, attn_out);
    // output projection (fp32 out)
    gemm8p<1><<<dim3(32, 8), dim3(512), 147456, stream>>>(
        attn_out, WoT, d_out, NTOK, 4096, 4096, 4096, 4096, 4096);
}

// Round 6
// 545.798 us; speedup vs baseline: 1.1083x; 1.0705x over previous
//
#include <hip/hip_runtime.h>
#include <hip/hip_bf16.h>
#include <math.h>

#define D_MODEL 4096
#define N_HEADS 128
#define LATENT  512
#define ROPE_D  64
#define HEAD_D  32
#define BATCH   2
#define SEQ     1024
#define NTOK    (BATCH*SEQ)

typedef unsigned short u16;
typedef __attribute__((ext_vector_type(8))) short bf16x8;
typedef __attribute__((ext_vector_type(4))) float f32x4;

__device__ __forceinline__ u16 f2bf(float f) {
    union { float f; unsigned u; } v; v.f = f;
    unsigned r = (v.u + 0x7fffu + ((v.u >> 16) & 1u)) >> 16;
    return (u16)r;
}

__device__ __forceinline__ void gl_lds16(const u16* g, u16* l) {
    __builtin_amdgcn_global_load_lds(
        (const __attribute__((address_space(1))) unsigned int*)g,
        (__attribute__((address_space(3))) unsigned int*)l, 16, 0, 0);
}

// ---------------- cast x: fp32 -> bf16 -------------------------------------
__global__ __launch_bounds__(256)
void cast_x_kernel(const float* __restrict__ in, u16* __restrict__ out)
{
    size_t i = ((size_t)blockIdx.x * 256 + threadIdx.x) * 8;
    float4 a = *(const float4*)(in + i);
    float4 b = *(const float4*)(in + i + 4);
    u16 o[8] = {f2bf(a.x), f2bf(a.y), f2bf(a.z), f2bf(a.w),
                f2bf(b.x), f2bf(b.y), f2bf(b.z), f2bf(b.w)};
    *(bf16x8*)(out + i) = *(bf16x8*)o;
}

// ---------- cast+transpose weights: W[K][N] fp32 -> Wt[N][K] bf16 ----------
// 32x32 tile, 1 float4 read + 1 8B write per thread. K,N multiples of 32.
__global__ __launch_bounds__(256)
void castT_kernel(const float* __restrict__ W, u16* __restrict__ Wt,
                  int K, int N)
{
    __shared__ float tile[32][33];
    const int tid = threadIdx.x;
    const int j0 = blockIdx.x * 32;   // N dim
    const int i0 = blockIdx.y * 32;   // K dim
    {
        int r = tid >> 3, c4 = (tid & 7) << 2;
        float4 v = *(const float4*)(W + (size_t)(i0 + r) * N + j0 + c4);
        tile[r][c4 + 0] = v.x; tile[r][c4 + 1] = v.y;
        tile[r][c4 + 2] = v.z; tile[r][c4 + 3] = v.w;
    }
    __syncthreads();
    {
        int n = tid >> 3, k4 = (tid & 7) << 2;
        u16 o[4] = { f2bf(tile[k4 + 0][n]), f2bf(tile[k4 + 1][n]),
                     f2bf(tile[k4 + 2][n]), f2bf(tile[k4 + 3][n]) };
        *(uint2*)(Wt + (size_t)(j0 + n) * K + i0 + k4) = *(uint2*)o;
    }
}

// ------- bf16 GEMM, m97 structure + M-fastest XCD chunk mapping ------------
template<int OUTF32>
__global__ __launch_bounds__(256)
void gemm_bf16(const u16* __restrict__ A, const u16* __restrict__ Bt,
               void* __restrict__ Cout, int M, int N, int K,
               int lda, int ldb, int ldc)
{
    __shared__ __align__(16) u16 As[128 * 64];
    __shared__ __align__(16) u16 Bs[128 * 64];

    const int tid  = threadIdx.x;
    const int lane = tid & 63;
    const int wave = tid >> 6;
    const int wr = wave >> 1, wc = wave & 1;
    // XCD chunk (nwg%8==0), M-fastest inside the chunk: B panel stays
    // L2-resident across the 16 M-blocks that reuse it.
    const int nwg  = gridDim.x * gridDim.y;
    const int orig = blockIdx.y * gridDim.x + blockIdx.x;
    const int swz  = (orig & 7) * (nwg >> 3) + (orig >> 3);
    const int bm = (swz % gridDim.y) * 128;
    const int bn = (swz / gridDim.y) * 128;
    const int l15 = lane & 15, lg = lane >> 4;

    f32x4 acc[4][4];
    #pragma unroll
    for (int i = 0; i < 4; ++i)
        #pragma unroll
        for (int j = 0; j < 4; ++j) acc[i][j] = (f32x4){0.f, 0.f, 0.f, 0.f};

    for (int kt = 0; kt < K; kt += 64) {
        __syncthreads();
        #pragma unroll
        for (int i = 0; i < 4; ++i) {          // stage A
            int f = i * 256 + tid;
            int row = f >> 3, c = f & 7;
            int sc = c ^ (row & 7);
            gl_lds16(A + (size_t)(bm + row) * lda + kt + sc * 8, As + f * 8);
        }
        #pragma unroll
        for (int i = 0; i < 4; ++i) {          // stage B
            int f = i * 256 + tid;
            int row = f >> 3, c = f & 7;
            int sc = c ^ (row & 7);
            gl_lds16(Bt + (size_t)(bn + row) * ldb + kt + sc * 8, Bs + f * 8);
        }
        __syncthreads();

        #pragma unroll
        for (int t = 0; t < 2; ++t) {
            bf16x8 af[4], bf[4];
            #pragma unroll
            for (int fm = 0; fm < 4; ++fm) {
                int row = wr * 64 + fm * 16 + l15;
                int c = (t * 4 + lg) ^ (row & 7);
                af[fm] = *(const bf16x8*)(As + row * 64 + c * 8);
            }
            #pragma unroll
            for (int fn = 0; fn < 4; ++fn) {
                int row = wc * 64 + fn * 16 + l15;
                int c = (t * 4 + lg) ^ (row & 7);
                bf[fn] = *(const bf16x8*)(Bs + row * 64 + c * 8);
            }
            #pragma unroll
            for (int fm = 0; fm < 4; ++fm)
                #pragma unroll
                for (int fn = 0; fn < 4; ++fn)
                    acc[fm][fn] = __builtin_amdgcn_mfma_f32_16x16x32_bf16(
                        af[fm], bf[fn], acc[fm][fn], 0, 0, 0);
        }
    }

    #pragma unroll
    for (int fm = 0; fm < 4; ++fm)
        #pragma unroll
        for (int fn = 0; fn < 4; ++fn)
            #pragma unroll
            for (int ri = 0; ri < 4; ++ri) {
                int row = bm + wr * 64 + fm * 16 + 4 * lg + ri;
                int col = bn + wc * 64 + fn * 16 + l15;
                if (col < N) {
                    float v = acc[fm][fn][ri];
                    if (OUTF32) ((float*)Cout)[(size_t)row * ldc + col] = v;
                    else        ((u16*)Cout)[(size_t)row * ldc + col] = f2bf(v);
                }
            }
}

// ======= 256x128 bf16 GEMM — fine-phase pipeline (kept for K=512 GEMMs) ====
template<int OUTF32>
__global__ __launch_bounds__(512)
void gemm8p(const u16* __restrict__ A, const u16* __restrict__ Bt,
            void* __restrict__ Cout, int M, int N, int K,
            int lda, int ldb, int ldc)
{
    constexpr int TILE_A = 256 * 64;
    constexpr int TILE_B = 128 * 64;
    constexpr int SLOT   = TILE_A + TILE_B;

    extern __shared__ __align__(16) u16 lds[];

    const int tid  = threadIdx.x;
    const int lane = tid & 63;
    const int wave = tid >> 6;
    const int wr = wave >> 2, wc = wave & 3;
    const int l15 = lane & 15, lg = lane >> 4;

    const int nwg  = gridDim.x * gridDim.y;
    const int orig = blockIdx.y * gridDim.x + blockIdx.x;
    const int swz  = (orig & 7) * (nwg >> 3) + (orig >> 3);
    const int bm = (swz % gridDim.y) * 256;
    const int bn = (swz / gridDim.y) * 128;

    const int NT = K >> 6;

    auto stageA = [&](int t) {
        u16* base = lds + (t % 3) * SLOT;
        const int kt = t << 6;
        #pragma unroll
        for (int it = 0; it < 4; ++it) {
            int f = it * 512 + tid;
            int row = f >> 3, c = f & 7;
            int sc = c ^ (row & 7);
            gl_lds16(A + (size_t)(bm + row) * lda + kt + sc * 8, base + f * 8);
        }
    };
    auto stageB = [&](int t) {
        u16* base = lds + (t % 3) * SLOT + TILE_A;
        const int kt = t << 6;
        #pragma unroll
        for (int it = 0; it < 2; ++it) {
            int f = it * 512 + tid;
            int row = f >> 3, c = f & 7;
            int sc = c ^ (row & 7);
            gl_lds16(Bt + (size_t)(bn + row) * ldb + kt + sc * 8, base + f * 8);
        }
    };

    f32x4 acc[8][2];
    #pragma unroll
    for (int m = 0; m < 8; ++m) {
        acc[m][0] = (f32x4){0.f, 0.f, 0.f, 0.f};
        acc[m][1] = (f32x4){0.f, 0.f, 0.f, 0.f};
    }

    stageA(0); stageB(0); stageA(1); stageB(1);
    asm volatile("s_waitcnt vmcnt(6)" ::: "memory");
    __builtin_amdgcn_sched_barrier(0);
    __builtin_amdgcn_s_barrier();
    __builtin_amdgcn_sched_barrier(0);

    for (int t = 0; t < NT; ++t) {
        const u16* bA = lds + (t % 3) * SLOT;
        const u16* bB = bA + TILE_A;
        #pragma unroll
        for (int s = 0; s < 2; ++s) {
            bf16x8 af[8], bfr[2];
            #pragma unroll
            for (int m = 0; m < 8; ++m) {
                int row = wr * 128 + m * 16 + l15;
                int ch = (s * 4 + lg) ^ (row & 7);
                af[m] = *(const bf16x8*)(bA + row * 64 + ch * 8);
            }
            #pragma unroll
            for (int n = 0; n < 2; ++n) {
                int row = wc * 32 + n * 16 + l15;
                int ch = (s * 4 + lg) ^ (row & 7);
                bfr[n] = *(const bf16x8*)(bB + row * 64 + ch * 8);
            }
            if (s == 0) {
                if (t + 2 < NT) stageA(t + 2);
            } else {
                if (t + 2 < NT) stageB(t + 2);
                if (t + 1 < NT) {
                    if (t + 2 < NT) asm volatile("s_waitcnt vmcnt(6)" ::: "memory");
                    else            asm volatile("s_waitcnt vmcnt(0)" ::: "memory");
                }
            }
            asm volatile("" ::: "memory");
            __builtin_amdgcn_sched_barrier(0);
            __builtin_amdgcn_s_barrier();
            __builtin_amdgcn_sched_barrier(0);
            __builtin_amdgcn_s_setprio(1);
            #pragma unroll
            for (int m = 0; m < 8; ++m) {
                acc[m][0] = __builtin_amdgcn_mfma_f32_16x16x32_bf16(af[m], bfr[0], acc[m][0], 0, 0, 0);
                acc[m][1] = __builtin_amdgcn_mfma_f32_16x16x32_bf16(af[m], bfr[1], acc[m][1], 0, 0, 0);
            }
            __builtin_amdgcn_s_setprio(0);
            __builtin_amdgcn_sched_barrier(0);
            __builtin_amdgcn_s_barrier();
            __builtin_amdgcn_sched_barrier(0);
            asm volatile("" ::: "memory");
        }
    }

    #pragma unroll
    for (int m = 0; m < 8; ++m)
        #pragma unroll
        for (int n = 0; n < 2; ++n)
            #pragma unroll
            for (int ri = 0; ri < 4; ++ri) {
                int row = bm + wr * 128 + m * 16 + 4 * lg + ri;
                int col = bn + wc * 32 + n * 16 + l15;
                float v = acc[m][n][ri];
                if (OUTF32) ((float*)Cout)[(size_t)row * ldc + col] = v;
                else        ((u16*)Cout)[(size_t)row * ldc + col] = f2bf(v);
            }
}

// ---------- transpose v_c (in C2, stride 8192, col base 4096) -> vt --------
__global__ __launch_bounds__(256)
void vtrans_kernel(const u16* __restrict__ vc, u16* __restrict__ vt)
{
    __shared__ __align__(16) u16 tile[64][72];
    const int tid = threadIdx.x;
    const int c0 = blockIdx.x * 64;
    const int s0 = blockIdx.y * 64;
    const int b  = blockIdx.z;
    #pragma unroll
    for (int it = 0; it < 2; ++it) {
        int e = it * 256 + tid;
        int r = e >> 3, c8 = e & 7;
        *(bf16x8*)&tile[r][c8 * 8] =
            *(const bf16x8*)(vc + (size_t)(b * SEQ + s0 + r) * 8192 + c0 + c8 * 8);
    }
    __syncthreads();
    #pragma unroll
    for (int it = 0; it < 2; ++it) {
        int e = it * 256 + tid;
        int d = e >> 3, c8 = e & 7;
        u16 o[8];
        #pragma unroll
        for (int j = 0; j < 8; ++j) o[j] = tile[c8 * 8 + j][d];
        *(bf16x8*)(vt + (size_t)(b * D_MODEL + c0 + d) * SEQ + s0 + c8 * 8) = *(bf16x8*)o;
    }
}

// ------- MFMA flash attention: counted-vmcnt pipeline (no barrier drain) ---
__global__ __launch_bounds__(256)
void attn_kernel(const u16* __restrict__ q_c, const u16* __restrict__ q_r,
                 const u16* __restrict__ k_c, const u16* __restrict__ k_r,
                 const u16* __restrict__ vt,  u16* __restrict__ attn_out)
{
    __shared__ __align__(16) u16 s_kc[2][64 * 32];
    __shared__ __align__(16) u16 s_kr[2][64 * 64];
    __shared__ __align__(16) u16 s_vt[2][32 * 64];
    __shared__ __align__(16) u16 s_p[4][16 * 64];

    const int tid  = threadIdx.x;
    const int lane = tid & 63;
    const int w    = tid >> 6;
    const int l15  = lane & 15, lg = lane >> 4;
    const int q0 = blockIdx.x * 64;
    const int h  = blockIdx.y;
    const int b  = blockIdx.z;
    const size_t bS = (size_t)b * SEQ;
    const int hc = h * HEAD_D;
    const float c2 = 0.1020620726159658f * 1.44269504088896f; // log2e/sqrt(96)

    const int qrow = q0 + w * 16 + l15;
    const bf16x8 qf0 = *(const bf16x8*)(q_c + (bS + qrow) * 4096 + hc + lg * 8);
    const bf16x8 qf1 = *(const bf16x8*)(q_r + (bS + qrow) * 9344 + h * ROPE_D + lg * 8);
    const bf16x8 qf2 = *(const bf16x8*)(q_r + (bS + qrow) * 9344 + h * ROPE_D + 32 + lg * 8);

    float m2 = -1e30f, lsum = 0.f;
    f32x4 oacc[2];
    oacc[0] = (f32x4){0.f, 0.f, 0.f, 0.f};
    oacc[1] = (f32x4){0.f, 0.f, 0.f, 0.f};

    // 4 global_load_lds per thread per stage
    auto stage = [&](int buf, int k0) {
        { int f = tid, r = f >> 2, c = f & 3;
          gl_lds16(k_c + (bS + k0 + r) * 8192 + hc + ((c ^ (r & 3)) << 3),
                   &s_kc[buf][f * 8]); }
        #pragma unroll
        for (int it = 0; it < 2; ++it) {
          int f = it * 256 + tid, r = f >> 3, c = f & 7;
          gl_lds16(k_r + (bS + k0 + r) * 9344 + ((c ^ (r & 7)) << 3),
                   &s_kr[buf][f * 8]); }
        { int f = tid, d = f >> 3, c = f & 7;
          gl_lds16(vt + ((size_t)b * D_MODEL + hc + d) * SEQ + k0 + ((c ^ (d & 7)) << 3),
                   &s_vt[buf][f * 8]); }
    };

    stage(0, 0);
    asm volatile("s_waitcnt vmcnt(0)" ::: "memory");
    __builtin_amdgcn_sched_barrier(0);
    __builtin_amdgcn_s_barrier();
    __builtin_amdgcn_sched_barrier(0);

    int cur = 0;
    for (int t = 0; t < SEQ / 64; ++t) {
        // issue next tile; confirm tile t (its 4 loads are the oldest)
        if (t + 1 < SEQ / 64) {
            stage(cur ^ 1, (t + 1) * 64);
            asm volatile("s_waitcnt vmcnt(4)" ::: "memory");
        } else {
            asm volatile("s_waitcnt vmcnt(0)" ::: "memory");
        }
        __builtin_amdgcn_sched_barrier(0);
        __builtin_amdgcn_s_barrier();            // (A) tile t visible everywhere
        __builtin_amdgcn_sched_barrier(0);

        f32x4 sc[4];
        #pragma unroll
        for (int fc = 0; fc < 4; ++fc) sc[fc] = (f32x4){0.f, 0.f, 0.f, 0.f};
        __builtin_amdgcn_s_setprio(1);
        #pragma unroll
        for (int fc = 0; fc < 4; ++fc) {
            int row = fc * 16 + l15;
            bf16x8 kb = *(const bf16x8*)&s_kc[cur][row * 32 + ((lg ^ (row & 3)) << 3)];
            sc[fc] = __builtin_amdgcn_mfma_f32_16x16x32_bf16(kb, qf0, sc[fc], 0, 0, 0);
        }
        #pragma unroll
        for (int tt = 0; tt < 2; ++tt) {
            bf16x8 qf = tt ? qf2 : qf1;
            #pragma unroll
            for (int fc = 0; fc < 4; ++fc) {
                int row = fc * 16 + l15;
                bf16x8 kb = *(const bf16x8*)&s_kr[cur][row * 64 + (((tt * 4 + lg) ^ (row & 7)) << 3)];
                sc[fc] = __builtin_amdgcn_mfma_f32_16x16x32_bf16(kb, qf, sc[fc], 0, 0, 0);
            }
        }
        __builtin_amdgcn_s_setprio(0);

        float tmx = sc[0][0];
        #pragma unroll
        for (int fc = 0; fc < 4; ++fc)
            #pragma unroll
            for (int ri = 0; ri < 4; ++ri)
                tmx = fmaxf(tmx, sc[fc][ri]);
        tmx = fmaxf(tmx, __shfl_xor(tmx, 16));
        tmx = fmaxf(tmx, __shfl_xor(tmx, 32));
        float tl2 = tmx * c2;
        if (!__all(tl2 <= m2 + 8.f)) {
            float mn = fmaxf(m2, tl2);
            float corr = exp2f(m2 - mn);
            m2 = mn;
            lsum *= corr;
            #pragma unroll
            for (int ri = 0; ri < 4; ++ri) {
                float cr = __shfl(corr, 4 * lg + ri);
                oacc[0][ri] *= cr; oacc[1][ri] *= cr;
            }
        }
        float rs = 0.f;
        unsigned pk0[4], pk1[4];
        #pragma unroll
        for (int fc = 0; fc < 4; ++fc) {
            float p0 = exp2f(fmaf(sc[fc][0], c2, -m2));
            float p1 = exp2f(fmaf(sc[fc][1], c2, -m2));
            float p2 = exp2f(fmaf(sc[fc][2], c2, -m2));
            float p3 = exp2f(fmaf(sc[fc][3], c2, -m2));
            rs += (p0 + p1) + (p2 + p3);
            asm("v_cvt_pk_bf16_f32 %0, %1, %2" : "=v"(pk0[fc]) : "v"(p0), "v"(p1));
            asm("v_cvt_pk_bf16_f32 %0, %1, %2" : "=v"(pk1[fc]) : "v"(p2), "v"(p3));
        }
        rs += __shfl_xor(rs, 16);
        rs += __shfl_xor(rs, 32);
        lsum += rs;
        #pragma unroll
        for (int fc = 0; fc < 4; ++fc) {
            int ch = (2 * fc + (lg >> 1)) ^ (l15 & 7);
            *(uint2*)&s_p[w][l15 * 64 + ch * 8 + 4 * (lg & 1)] =
                make_uint2(pk0[fc], pk1[fc]);
        }

        __builtin_amdgcn_s_setprio(1);
        #pragma unroll
        for (int t2 = 0; t2 < 2; ++t2) {
            bf16x8 pa = *(const bf16x8*)&s_p[w][l15 * 64 + (((t2 * 4 + lg) ^ (l15 & 7)) << 3)];
            #pragma unroll
            for (int fd = 0; fd < 2; ++fd) {
                int row = fd * 16 + l15;
                bf16x8 vb = *(const bf16x8*)&s_vt[cur][row * 64 + (((t2 * 4 + lg) ^ (row & 7)) << 3)];
                oacc[fd] = __builtin_amdgcn_mfma_f32_16x16x32_bf16(pa, vb, oacc[fd], 0, 0, 0);
            }
        }
        __builtin_amdgcn_s_setprio(0);

        // (B) all my LDS reads retired; then block-wide rendezvous so the
        // next stage() can't overwrite a buffer someone still reads.
        asm volatile("s_waitcnt lgkmcnt(0)" ::: "memory");
        __builtin_amdgcn_sched_barrier(0);
        __builtin_amdgcn_s_barrier();
        __builtin_amdgcn_sched_barrier(0);
        cur ^= 1;
    }

    #pragma unroll
    for (int ri = 0; ri < 4; ++ri) {
        float ls = __shfl(lsum, 4 * lg + ri);
        float inv = 1.f / ls;
        int row = q0 + w * 16 + 4 * lg + ri;
        attn_out[(bS + row) * 4096 + hc + l15]      = f2bf(oacc[0][ri] * inv);
        attn_out[(bS + row) * 4096 + hc + 16 + l15] = f2bf(oacc[1][ri] * inv);
    }
}

// ---------------------------------------------------------------------------
extern "C" void kernel_launch(void* const* d_in, const int* in_sizes, int n_in,
                              void* d_out, int out_size, void* d_ws, size_t ws_size,
                              hipStream_t stream)
{
    (void)in_sizes; (void)n_in; (void)out_size; (void)ws_size;

    const float* x        = (const float*)d_in[0];
    const float* Wq_down  = (const float*)d_in[1];
    const float* Wq_up    = (const float*)d_in[2];
    const float* Wq_rope  = (const float*)d_in[3];
    const float* Wkv_down = (const float*)d_in[4];
    const float* Wk_up    = (const float*)d_in[5];
    const float* Wv_up    = (const float*)d_in[6];
    const float* Wk_rope  = (const float*)d_in[7];
    const float* Wo       = (const float*)d_in[8];

    // workspace (u16 units), ~179 MB total
    u16* ws   = (u16*)d_ws;
    u16* xb   = ws;                                  //  8,388,608 (x bf16; later attn_out)
    u16* BigT = xb + (size_t)8388608;                // 38,797,312 (9472 x 4096)
    u16* UpT  = BigT + (size_t)38797312;             //  4,194,304 (8192 x 512)
    u16* WuqT = UpT + (size_t)4194304;               //  2,097,152 (4096 x 512)
    u16* C_big= WuqT + (size_t)2097152;              // 19,136,512 (2048 x 9344)
    u16* C2   = C_big + (size_t)19136512;            // 16,777,216 (2048 x 8192: k_c|v_c)
    u16* WoT  = BigT;                                // after GEMM1
    u16* vt   = BigT + (size_t)16777216;
    u16* q_c  = BigT + (size_t)25165824;
    u16* attn_out = xb;

    dim3 blk(256);

    (void)hipFuncSetAttribute((const void*)&gemm8p<0>,
                              hipFuncAttributeMaxDynamicSharedMemorySize, 147456);

    // zero pad rows 9280..9343 of BigT (Wk_rope pad inside N=9344)
    hipMemsetAsync(BigT + (size_t)9280 * 4096, 0, (size_t)64 * 4096 * 2, stream);
    hipLaunchKernelGGL(cast_x_kernel, dim3(4096), blk, 0, stream, x, xb);
    // BigT rows: [0,8192)=Wq_rope^T, [8192,8704)=Wq_down^T, [8704,9216)=Wkv_down^T, [9216,9280)=Wk_rope^T
    hipLaunchKernelGGL(castT_kernel, dim3(256, 128), blk, 0, stream, Wq_rope, BigT, 4096, 8192);
    hipLaunchKernelGGL(castT_kernel, dim3(16, 128), blk, 0, stream, Wq_down, BigT + (size_t)8192 * 4096, 4096, 512);
    hipLaunchKernelGGL(castT_kernel, dim3(16, 128), blk, 0, stream, Wkv_down, BigT + (size_t)8704 * 4096, 4096, 512);
    hipLaunchKernelGGL(castT_kernel, dim3(2, 128), blk, 0, stream, Wk_rope, BigT + (size_t)9216 * 4096, 4096, 64);
    hipLaunchKernelGGL(castT_kernel, dim3(128, 16), blk, 0, stream, Wk_up, UpT, 512, 4096);
    hipLaunchKernelGGL(castT_kernel, dim3(128, 16), blk, 0, stream, Wv_up, UpT + (size_t)4096 * 512, 512, 4096);
    hipLaunchKernelGGL(castT_kernel, dim3(128, 16), blk, 0, stream, Wq_up, WuqT, 512, 4096);

    // GEMM1: C_big = xb @ BigT^T  (M=2048, N=9344, K=4096) — m97 structure
    gemm_bf16<0><<<dim3(73, 16), blk, 0, stream>>>(
        xb, BigT, C_big, NTOK, 9344, 4096, 4096, 4096, 9344);
    // Wo^T into freed BigT
    hipLaunchKernelGGL(castT_kernel, dim3(128, 128), blk, 0, stream, Wo, WoT, 4096, 4096);
    // GEMM2: k_c|v_c = c_kv @ [Wk_up|Wv_up]^T  (N=8192, K=512) — gemm8p
    gemm8p<0><<<dim3(64, 8), dim3(512), 147456, stream>>>(
        C_big + 8704, UpT, C2, NTOK, 8192, 512, 9344, 512, 8192);
    // GEMM3: q_c = c_q @ Wq_up^T  (N=4096, K=512) — gemm8p
    gemm8p<0><<<dim3(32, 8), dim3(512), 147456, stream>>>(
        C_big + 8192, WuqT, q_c, NTOK, 4096, 512, 9344, 512, 4096);
    // V transpose, attention
    hipLaunchKernelGGL(vtrans_kernel, dim3(64, 16, 2), blk, 0, stream, C2 + 4096, vt);
    hipLaunchKernelGGL(attn_kernel, dim3(16, 128, 2), blk, 0, stream,
                       q_c, C_big, C2, C_big + 9216, vt, attn_out);
    // output projection (fp32 out) — m97 structure
    gemm_bf16<1><<<dim3(32, 16), blk, 0, stream>>>(
        attn_out, WoT, d_out, NTOK, 4096, 4096, 4096, 4096, 4096);
}

// Round 7
// 512.684 us; speedup vs baseline: 1.1799x; 1.0646x over previous
//
#include <hip/hip_runtime.h>
#include <hip/hip_bf16.h>
#include <math.h>

#define D_MODEL 4096
#define N_HEADS 128
#define LATENT  512
#define ROPE_D  64
#define HEAD_D  32
#define BATCH   2
#define SEQ     1024
#define NTOK    (BATCH*SEQ)

typedef unsigned short u16;
typedef __attribute__((ext_vector_type(8))) short bf16x8;
typedef __attribute__((ext_vector_type(4))) float f32x4;

__device__ __forceinline__ u16 f2bf(float f) {
    union { float f; unsigned u; } v; v.f = f;
    unsigned r = (v.u + 0x7fffu + ((v.u >> 16) & 1u)) >> 16;
    return (u16)r;
}

__device__ __forceinline__ void gl_lds16(const u16* g, u16* l) {
    __builtin_amdgcn_global_load_lds(
        (const __attribute__((address_space(1))) unsigned int*)g,
        (__attribute__((address_space(3))) unsigned int*)l, 16, 0, 0);
}

// ---- 32x32 cast+transpose tile: W[K][N] fp32 -> Wt[N][K] bf16 -------------
__device__ __forceinline__ void castT_tile(const float* __restrict__ W,
                                           u16* __restrict__ Wt,
                                           int K, int N, int jx, int jy,
                                           float (*tile)[33])
{
    const int tid = threadIdx.x;
    const int j0 = jx * 32, i0 = jy * 32;
    {
        int r = tid >> 3, c4 = (tid & 7) << 2;
        float4 v = *(const float4*)(W + (size_t)(i0 + r) * N + j0 + c4);
        tile[r][c4 + 0] = v.x; tile[r][c4 + 1] = v.y;
        tile[r][c4 + 2] = v.z; tile[r][c4 + 3] = v.w;
    }
    __syncthreads();
    {
        int n = tid >> 3, k4 = (tid & 7) << 2;
        u16 o[4] = { f2bf(tile[k4 + 0][n]), f2bf(tile[k4 + 1][n]),
                     f2bf(tile[k4 + 2][n]), f2bf(tile[k4 + 3][n]) };
        *(uint2*)(Wt + (size_t)(j0 + n) * K + i0 + k4) = *(uint2*)o;
    }
}

// ---- m97 GEMM core: C[128x128 tile] = A[M,K] @ Bt[N,K]^T ------------------
__device__ __forceinline__ void gemm_core(const u16* __restrict__ A,
                                          const u16* __restrict__ Bt,
                                          void* __restrict__ Cout,
                                          int N, int K, int lda, int ldb, int ldc,
                                          int bm, int bn, u16* As, u16* Bs,
                                          int OUTF32)
{
    const int tid  = threadIdx.x;
    const int lane = tid & 63;
    const int wave = tid >> 6;
    const int wr = wave >> 1, wc = wave & 1;
    const int l15 = lane & 15, lg = lane >> 4;

    f32x4 acc[4][4];
    #pragma unroll
    for (int i = 0; i < 4; ++i)
        #pragma unroll
        for (int j = 0; j < 4; ++j) acc[i][j] = (f32x4){0.f, 0.f, 0.f, 0.f};

    for (int kt = 0; kt < K; kt += 64) {
        __syncthreads();
        #pragma unroll
        for (int i = 0; i < 4; ++i) {          // stage A
            int f = i * 256 + tid;
            int row = f >> 3, c = f & 7;
            int sc = c ^ (row & 7);
            gl_lds16(A + (size_t)(bm + row) * lda + kt + sc * 8, As + f * 8);
        }
        #pragma unroll
        for (int i = 0; i < 4; ++i) {          // stage B
            int f = i * 256 + tid;
            int row = f >> 3, c = f & 7;
            int sc = c ^ (row & 7);
            gl_lds16(Bt + (size_t)(bn + row) * ldb + kt + sc * 8, Bs + f * 8);
        }
        __syncthreads();

        #pragma unroll
        for (int t = 0; t < 2; ++t) {
            bf16x8 af[4], bf[4];
            #pragma unroll
            for (int fm = 0; fm < 4; ++fm) {
                int row = wr * 64 + fm * 16 + l15;
                int c = (t * 4 + lg) ^ (row & 7);
                af[fm] = *(const bf16x8*)(As + row * 64 + c * 8);
            }
            #pragma unroll
            for (int fn = 0; fn < 4; ++fn) {
                int row = wc * 64 + fn * 16 + l15;
                int c = (t * 4 + lg) ^ (row & 7);
                bf[fn] = *(const bf16x8*)(Bs + row * 64 + c * 8);
            }
            #pragma unroll
            for (int fm = 0; fm < 4; ++fm)
                #pragma unroll
                for (int fn = 0; fn < 4; ++fn)
                    acc[fm][fn] = __builtin_amdgcn_mfma_f32_16x16x32_bf16(
                        af[fm], bf[fn], acc[fm][fn], 0, 0, 0);
        }
    }

    #pragma unroll
    for (int fm = 0; fm < 4; ++fm)
        #pragma unroll
        for (int fn = 0; fn < 4; ++fn)
            #pragma unroll
            for (int ri = 0; ri < 4; ++ri) {
                int row = bm + wr * 64 + fm * 16 + 4 * lg + ri;
                int col = bn + wc * 64 + fn * 16 + l15;
                float v = acc[fm][fn][ri];
                if (OUTF32) ((float*)Cout)[(size_t)row * ldc + col] = v;
                else        ((u16*)Cout)[(size_t)row * ldc + col] = f2bf(v);
            }
}

// ---- standalone GEMM (M-fastest XCD chunk mapping; nwg % 8 == 0) ----------
template<int OUTF32>
__global__ __launch_bounds__(256)
void gemm_bf16(const u16* __restrict__ A, const u16* __restrict__ Bt,
               void* __restrict__ Cout, int N, int K,
               int lda, int ldb, int ldc)
{
    __shared__ __align__(16) u16 As[128 * 64];
    __shared__ __align__(16) u16 Bs[128 * 64];
    const int nwg  = gridDim.x * gridDim.y;
    const int orig = blockIdx.y * gridDim.x + blockIdx.x;
    const int swz  = (orig & 7) * (nwg >> 3) + (orig >> 3);
    const int bm = (swz % gridDim.y) * 128;
    const int bn = (swz / gridDim.y) * 128;
    gemm_core(A, Bt, Cout, N, K, lda, ldb, ldc, bm, bn, As, Bs, OUTF32);
}

// ---- prep: cast_x + 7 weight transposes + pad zeroing, ONE dispatch -------
__global__ __launch_bounds__(256)
void prep_kernel(const float* __restrict__ x, u16* __restrict__ xb,
                 const float* __restrict__ Wq_rope, const float* __restrict__ Wq_down,
                 const float* __restrict__ Wkv_down, const float* __restrict__ Wk_rope,
                 const float* __restrict__ Wk_up, const float* __restrict__ Wv_up,
                 const float* __restrict__ Wq_up,
                 u16* __restrict__ BigT, u16* __restrict__ UpT, u16* __restrict__ WuqT)
{
    __shared__ float tile[32][33];
    const int tid = threadIdx.x;
    int id = blockIdx.x;
    if (id < 4096) {                          // cast x -> bf16
        size_t i = ((size_t)id * 256 + tid) * 8;
        float4 a = *(const float4*)(x + i);
        float4 b = *(const float4*)(x + i + 4);
        u16 o[8] = {f2bf(a.x), f2bf(a.y), f2bf(a.z), f2bf(a.w),
                    f2bf(b.x), f2bf(b.y), f2bf(b.z), f2bf(b.w)};
        *(bf16x8*)(xb + i) = *(bf16x8*)o;
        return;
    }
    id -= 4096;
    if (id < 32768) { castT_tile(Wq_rope, BigT, 4096, 8192, id & 255, id >> 8, tile); return; }
    id -= 32768;
    if (id < 2048) { castT_tile(Wq_down, BigT + (size_t)8192 * 4096, 4096, 512, id & 15, id >> 4, tile); return; }
    id -= 2048;
    if (id < 2048) { castT_tile(Wkv_down, BigT + (size_t)8704 * 4096, 4096, 512, id & 15, id >> 4, tile); return; }
    id -= 2048;
    if (id < 256) { castT_tile(Wk_rope, BigT + (size_t)9216 * 4096, 4096, 64, id & 1, id >> 1, tile); return; }
    id -= 256;
    if (id < 2048) { castT_tile(Wk_up, UpT, 512, 4096, id & 127, id >> 7, tile); return; }
    id -= 2048;
    if (id < 2048) { castT_tile(Wv_up, UpT + (size_t)4096 * 512, 512, 4096, id & 127, id >> 7, tile); return; }
    id -= 2048;
    if (id < 2048) { castT_tile(Wq_up, WuqT, 512, 4096, id & 127, id >> 7, tile); return; }
    id -= 2048;
    {   // zero pad rows 9280..9343 of BigT (id in [0,64))
        u16* dst = BigT + ((size_t)9280 + id) * 4096;
        bf16x8 z = (bf16x8){0, 0, 0, 0, 0, 0, 0, 0};
        *(bf16x8*)(dst + tid * 8) = z;
        *(bf16x8*)(dst + 2048 + tid * 8) = z;
    }
}

// ---- fused2: GEMM2 (k|v up) + GEMM3 (q up) + Wo^T transpose, ONE dispatch -
__global__ __launch_bounds__(256)
void fused2_kernel(const u16* __restrict__ Cbig, const u16* __restrict__ UpT,
                   u16* __restrict__ C2, const u16* __restrict__ WuqT,
                   u16* __restrict__ q_c, const float* __restrict__ Wo,
                   u16* __restrict__ WoT)
{
    __shared__ __align__(16) u16 As[128 * 64];
    __shared__ __align__(16) u16 Bs[128 * 64];
    int id = blockIdx.x;
    if (id < 1024) {       // GEMM2: k_c|v_c = c_kv @ [Wk_up|Wv_up]^T
        const int swz = (id & 7) * 128 + (id >> 3);
        const int bm = (swz & 15) * 128, bn = (swz >> 4) * 128;
        gemm_core(Cbig + 8704, UpT, C2, 8192, 512, 9344, 512, 8192, bm, bn, As, Bs, 0);
        return;
    }
    id -= 1024;
    if (id < 512) {        // GEMM3: q_c = c_q @ Wq_up^T
        const int swz = (id & 7) * 64 + (id >> 3);
        const int bm = (swz & 15) * 128, bn = (swz >> 4) * 128;
        gemm_core(Cbig + 8192, WuqT, q_c, 4096, 512, 9344, 512, 4096, bm, bn, As, Bs, 0);
        return;
    }
    id -= 512;
    {                      // Wo^T: 4096x4096, 16384 tiles
        float (*tile)[33] = reinterpret_cast<float(*)[33]>(As);
        castT_tile(Wo, WoT, 4096, 4096, id & 127, id >> 7, tile);
    }
}

// ---------- transpose v_c (in C2, stride 8192, col base 4096) -> vt --------
__global__ __launch_bounds__(256)
void vtrans_kernel(const u16* __restrict__ vc, u16* __restrict__ vt)
{
    __shared__ __align__(16) u16 tile[64][72];
    const int tid = threadIdx.x;
    const int c0 = blockIdx.x * 64;
    const int s0 = blockIdx.y * 64;
    const int b  = blockIdx.z;
    #pragma unroll
    for (int it = 0; it < 2; ++it) {
        int e = it * 256 + tid;
        int r = e >> 3, c8 = e & 7;
        *(bf16x8*)&tile[r][c8 * 8] =
            *(const bf16x8*)(vc + (size_t)(b * SEQ + s0 + r) * 8192 + c0 + c8 * 8);
    }
    __syncthreads();
    #pragma unroll
    for (int it = 0; it < 2; ++it) {
        int e = it * 256 + tid;
        int d = e >> 3, c8 = e & 7;
        u16 o[8];
        #pragma unroll
        for (int j = 0; j < 8; ++j) o[j] = tile[c8 * 8 + j][d];
        *(bf16x8*)(vt + (size_t)(b * D_MODEL + c0 + d) * SEQ + s0 + c8 * 8) = *(bf16x8*)o;
    }
}

// ------- MFMA flash attention: counted-vmcnt pipeline (no barrier drain) ---
__global__ __launch_bounds__(256)
void attn_kernel(const u16* __restrict__ q_c, const u16* __restrict__ q_r,
                 const u16* __restrict__ k_c, const u16* __restrict__ k_r,
                 const u16* __restrict__ vt,  u16* __restrict__ attn_out)
{
    __shared__ __align__(16) u16 s_kc[2][64 * 32];
    __shared__ __align__(16) u16 s_kr[2][64 * 64];
    __shared__ __align__(16) u16 s_vt[2][32 * 64];
    __shared__ __align__(16) u16 s_p[4][16 * 64];

    const int tid  = threadIdx.x;
    const int lane = tid & 63;
    const int w    = tid >> 6;
    const int l15  = lane & 15, lg = lane >> 4;
    const int q0 = blockIdx.x * 64;
    const int h  = blockIdx.y;
    const int b  = blockIdx.z;
    const size_t bS = (size_t)b * SEQ;
    const int hc = h * HEAD_D;
    const float c2 = 0.1020620726159658f * 1.44269504088896f; // log2e/sqrt(96)

    const int qrow = q0 + w * 16 + l15;
    const bf16x8 qf0 = *(const bf16x8*)(q_c + (bS + qrow) * 4096 + hc + lg * 8);
    const bf16x8 qf1 = *(const bf16x8*)(q_r + (bS + qrow) * 9344 + h * ROPE_D + lg * 8);
    const bf16x8 qf2 = *(const bf16x8*)(q_r + (bS + qrow) * 9344 + h * ROPE_D + 32 + lg * 8);

    float m2 = -1e30f, lsum = 0.f;
    f32x4 oacc[2];
    oacc[0] = (f32x4){0.f, 0.f, 0.f, 0.f};
    oacc[1] = (f32x4){0.f, 0.f, 0.f, 0.f};

    auto stage = [&](int buf, int k0) {
        { int f = tid, r = f >> 2, c = f & 3;
          gl_lds16(k_c + (bS + k0 + r) * 8192 + hc + ((c ^ (r & 3)) << 3),
                   &s_kc[buf][f * 8]); }
        #pragma unroll
        for (int it = 0; it < 2; ++it) {
          int f = it * 256 + tid, r = f >> 3, c = f & 7;
          gl_lds16(k_r + (bS + k0 + r) * 9344 + ((c ^ (r & 7)) << 3),
                   &s_kr[buf][f * 8]); }
        { int f = tid, d = f >> 3, c = f & 7;
          gl_lds16(vt + ((size_t)b * D_MODEL + hc + d) * SEQ + k0 + ((c ^ (d & 7)) << 3),
                   &s_vt[buf][f * 8]); }
    };

    stage(0, 0);
    asm volatile("s_waitcnt vmcnt(0)" ::: "memory");
    __builtin_amdgcn_sched_barrier(0);
    __builtin_amdgcn_s_barrier();
    __builtin_amdgcn_sched_barrier(0);

    int cur = 0;
    for (int t = 0; t < SEQ / 64; ++t) {
        if (t + 1 < SEQ / 64) {
            stage(cur ^ 1, (t + 1) * 64);
            asm volatile("s_waitcnt vmcnt(4)" ::: "memory");
        } else {
            asm volatile("s_waitcnt vmcnt(0)" ::: "memory");
        }
        __builtin_amdgcn_sched_barrier(0);
        __builtin_amdgcn_s_barrier();            // (A) tile t visible everywhere
        __builtin_amdgcn_sched_barrier(0);

        f32x4 sc[4];
        #pragma unroll
        for (int fc = 0; fc < 4; ++fc) sc[fc] = (f32x4){0.f, 0.f, 0.f, 0.f};
        __builtin_amdgcn_s_setprio(1);
        #pragma unroll
        for (int fc = 0; fc < 4; ++fc) {
            int row = fc * 16 + l15;
            bf16x8 kb = *(const bf16x8*)&s_kc[cur][row * 32 + ((lg ^ (row & 3)) << 3)];
            sc[fc] = __builtin_amdgcn_mfma_f32_16x16x32_bf16(kb, qf0, sc[fc], 0, 0, 0);
        }
        #pragma unroll
        for (int tt = 0; tt < 2; ++tt) {
            bf16x8 qf = tt ? qf2 : qf1;
            #pragma unroll
            for (int fc = 0; fc < 4; ++fc) {
                int row = fc * 16 + l15;
                bf16x8 kb = *(const bf16x8*)&s_kr[cur][row * 64 + (((tt * 4 + lg) ^ (row & 7)) << 3)];
                sc[fc] = __builtin_amdgcn_mfma_f32_16x16x32_bf16(kb, qf, sc[fc], 0, 0, 0);
            }
        }
        __builtin_amdgcn_s_setprio(0);

        float tmx = sc[0][0];
        #pragma unroll
        for (int fc = 0; fc < 4; ++fc)
            #pragma unroll
            for (int ri = 0; ri < 4; ++ri)
                tmx = fmaxf(tmx, sc[fc][ri]);
        tmx = fmaxf(tmx, __shfl_xor(tmx, 16));
        tmx = fmaxf(tmx, __shfl_xor(tmx, 32));
        float tl2 = tmx * c2;
        if (!__all(tl2 <= m2 + 8.f)) {
            float mn = fmaxf(m2, tl2);
            float corr = exp2f(m2 - mn);
            m2 = mn;
            lsum *= corr;
            #pragma unroll
            for (int ri = 0; ri < 4; ++ri) {
                float cr = __shfl(corr, 4 * lg + ri);
                oacc[0][ri] *= cr; oacc[1][ri] *= cr;
            }
        }
        float rs = 0.f;
        unsigned pk0[4], pk1[4];
        #pragma unroll
        for (int fc = 0; fc < 4; ++fc) {
            float p0 = exp2f(fmaf(sc[fc][0], c2, -m2));
            float p1 = exp2f(fmaf(sc[fc][1], c2, -m2));
            float p2 = exp2f(fmaf(sc[fc][2], c2, -m2));
            float p3 = exp2f(fmaf(sc[fc][3], c2, -m2));
            rs += (p0 + p1) + (p2 + p3);
            asm("v_cvt_pk_bf16_f32 %0, %1, %2" : "=v"(pk0[fc]) : "v"(p0), "v"(p1));
            asm("v_cvt_pk_bf16_f32 %0, %1, %2" : "=v"(pk1[fc]) : "v"(p2), "v"(p3));
        }
        rs += __shfl_xor(rs, 16);
        rs += __shfl_xor(rs, 32);
        lsum += rs;
        #pragma unroll
        for (int fc = 0; fc < 4; ++fc) {
            int ch = (2 * fc + (lg >> 1)) ^ (l15 & 7);
            *(uint2*)&s_p[w][l15 * 64 + ch * 8 + 4 * (lg & 1)] =
                make_uint2(pk0[fc], pk1[fc]);
        }

        __builtin_amdgcn_s_setprio(1);
        #pragma unroll
        for (int t2 = 0; t2 < 2; ++t2) {
            bf16x8 pa = *(const bf16x8*)&s_p[w][l15 * 64 + (((t2 * 4 + lg) ^ (l15 & 7)) << 3)];
            #pragma unroll
            for (int fd = 0; fd < 2; ++fd) {
                int row = fd * 16 + l15;
                bf16x8 vb = *(const bf16x8*)&s_vt[cur][row * 64 + (((t2 * 4 + lg) ^ (row & 7)) << 3)];
                oacc[fd] = __builtin_amdgcn_mfma_f32_16x16x32_bf16(pa, vb, oacc[fd], 0, 0, 0);
            }
        }
        __builtin_amdgcn_s_setprio(0);

        asm volatile("s_waitcnt lgkmcnt(0)" ::: "memory");
        __builtin_amdgcn_sched_barrier(0);
        __builtin_amdgcn_s_barrier();            // (B) safe to restage
        __builtin_amdgcn_sched_barrier(0);
        cur ^= 1;
    }

    #pragma unroll
    for (int ri = 0; ri < 4; ++ri) {
        float ls = __shfl(lsum, 4 * lg + ri);
        float inv = 1.f / ls;
        int row = q0 + w * 16 + 4 * lg + ri;
        attn_out[(bS + row) * 4096 + hc + l15]      = f2bf(oacc[0][ri] * inv);
        attn_out[(bS + row) * 4096 + hc + 16 + l15] = f2bf(oacc[1][ri] * inv);
    }
}

// ---------------------------------------------------------------------------
extern "C" void kernel_launch(void* const* d_in, const int* in_sizes, int n_in,
                              void* d_out, int out_size, void* d_ws, size_t ws_size,
                              hipStream_t stream)
{
    (void)in_sizes; (void)n_in; (void)out_size; (void)ws_size;

    const float* x        = (const float*)d_in[0];
    const float* Wq_down  = (const float*)d_in[1];
    const float* Wq_up    = (const float*)d_in[2];
    const float* Wq_rope  = (const float*)d_in[3];
    const float* Wkv_down = (const float*)d_in[4];
    const float* Wk_up    = (const float*)d_in[5];
    const float* Wv_up    = (const float*)d_in[6];
    const float* Wk_rope  = (const float*)d_in[7];
    const float* Wo       = (const float*)d_in[8];

    // workspace (u16 units), ~179 MB total
    u16* ws   = (u16*)d_ws;
    u16* xb   = ws;                                  //  8,388,608 (x bf16; later attn_out)
    u16* BigT = xb + (size_t)8388608;                // 38,797,312 (9472 x 4096)
    u16* UpT  = BigT + (size_t)38797312;             //  4,194,304 (8192 x 512)
    u16* WuqT = UpT + (size_t)4194304;               //  2,097,152 (4096 x 512)
    u16* C_big= WuqT + (size_t)2097152;              // 19,136,512 (2048 x 9344)
    u16* C2   = C_big + (size_t)19136512;            // 16,777,216 (2048 x 8192: k_c|v_c)
    u16* WoT  = BigT;                                // after GEMM1
    u16* vt   = BigT + (size_t)16777216;
    u16* q_c  = BigT + (size_t)25165824;
    u16* attn_out = xb;

    dim3 blk(256);

    // 1. all preprocessing in one dispatch
    hipLaunchKernelGGL(prep_kernel, dim3(47424), blk, 0, stream,
                       x, xb, Wq_rope, Wq_down, Wkv_down, Wk_rope,
                       Wk_up, Wv_up, Wq_up, BigT, UpT, WuqT);
    // 2. GEMM1: C_big = xb @ BigT^T  (M=2048, N=9344, K=4096)
    gemm_bf16<0><<<dim3(73, 16), blk, 0, stream>>>(
        xb, BigT, C_big, 9344, 4096, 4096, 4096, 9344);
    // 3. GEMM2 + GEMM3 + Wo^T in one dispatch (gemm blocks first)
    hipLaunchKernelGGL(fused2_kernel, dim3(1024 + 512 + 16384), blk, 0, stream,
                       C_big, UpT, C2, WuqT, q_c, Wo, WoT);
    // 4. V transpose
    hipLaunchKernelGGL(vtrans_kernel, dim3(64, 16, 2), blk, 0, stream, C2 + 4096, vt);
    // 5. attention
    hipLaunchKernelGGL(attn_kernel, dim3(16, 128, 2), blk, 0, stream,
                       q_c, C_big, C2, C_big + 9216, vt, attn_out);
    // 6. output projection (fp32 out)
    gemm_bf16<1><<<dim3(32, 16), blk, 0, stream>>>(
        attn_out, WoT, d_out, 4096, 4096, 4096, 4096, 4096);
}